// Round 1
// baseline (290.175 us; speedup 1.0000x reference)
//
#include <hip/hip_runtime.h>
#include <hip/hip_bf16.h>

// Problem constants (set_attention): B=4, Nq=Nk=2048, D_IN=512, H=8, HS=64
#define BB   4
#define NQ   2048
#define NKK  2048
#define DIN  512
#define NH   8
#define HS   64
#define HD   512  // NH*HS

typedef __hip_bfloat16 bf16;
typedef unsigned short ushort_t;
typedef __attribute__((ext_vector_type(8))) short short8;   // 8 bf16 (4 VGPRs)
typedef __attribute__((ext_vector_type(4))) float f32x4;    // MFMA 16x16 C/D
typedef __attribute__((ext_vector_type(16))) float f32x16;  // MFMA 32x32 C/D

__device__ __forceinline__ unsigned short f2bu(float x) {
  bf16 h = __float2bfloat16(x);
  return *(unsigned short*)&h;
}

// ---------------------------------------------------------------------------
// Kernel 0: weight transpose + bf16 convert.
// z<3:  W[512k][512n] f32 -> Wt_z[n][k] bf16   (64x64 tiles via LDS)
// z==3: Wh[512k][64n] f32 -> Wht[n][k] bf16
// ---------------------------------------------------------------------------
__global__ __launch_bounds__(256) void wtrans_kernel(
    const float* __restrict__ Wq, const float* __restrict__ Wk,
    const float* __restrict__ Wv, const float* __restrict__ Wh,
    ushort_t* __restrict__ Wt, ushort_t* __restrict__ Wht) {
  const int z = blockIdx.z;
  const float* src;
  ushort_t* dst;
  int S;  // source row length (n-dim)
  if (z < 3) {
    src = (z == 0) ? Wq : (z == 1) ? Wk : Wv;
    dst = Wt + (size_t)z * 512 * 512;
    S = 512;
  } else {
    if (blockIdx.y != 0) return;
    src = Wh;
    dst = Wht;
    S = 64;
  }
  const int k0 = blockIdx.x * 64;
  const int n0 = (z < 3) ? blockIdx.y * 64 : 0;

  __shared__ ushort_t Ls[64 * 72];
  const int tid = threadIdx.x;
  {
    int r = tid >> 2, cb = (tid & 3) * 16;
    const float* sp = src + (size_t)(k0 + r) * S + n0 + cb;
#pragma unroll
    for (int ii = 0; ii < 4; ++ii) {
      float4 f = *(const float4*)(sp + ii * 4);
      __align__(8) ushort_t t4[4] = {f2bu(f.x), f2bu(f.y), f2bu(f.z), f2bu(f.w)};
      *(uint2*)(&Ls[r * 72 + cb + ii * 4]) = *(uint2*)t4;
    }
  }
  __syncthreads();
  {
    int rr = tid >> 2, tb = (tid & 3) * 16;
    __align__(16) ushort_t tmp[16];
#pragma unroll
    for (int j = 0; j < 16; ++j) tmp[j] = Ls[(tb + j) * 72 + rr];
    ushort_t* dp = dst + (size_t)(n0 + rr) * 512 + k0 + tb;
    *(int4*)dp       = ((int4*)tmp)[0];
    *(int4*)(dp + 8) = ((int4*)tmp)[1];
  }
}

// ---------------------------------------------------------------------------
// Kernel 1: QKV projections, bf16 MFMA, double-buffered. Y = X @ W.
// ---------------------------------------------------------------------------
__global__ __launch_bounds__(256) void proj_kernel(
    const float* __restrict__ q, const float* __restrict__ k,
    const ushort_t* __restrict__ Wt, ushort_t* __restrict__ Qf,
    ushort_t* __restrict__ Kf, ushort_t* __restrict__ Vf) {
  const int z = blockIdx.z;
  const float* X = (z == 0) ? q : k;
  const ushort_t* Wz = Wt + (size_t)z * 512 * 512;
  ushort_t* Y = (z == 0) ? Qf : (z == 1) ? Kf : Vf;
  const float sc = (z == 0) ? 0.125f : 1.0f;  // fold 1/sqrt(64) into Q

  __shared__ ushort_t As[2 * 128 * 40];  // [buf][m][k]
  __shared__ ushort_t Bs[2 * 128 * 40];  // [buf][n][k]

  const int tid  = threadIdx.x;
  const int lane = tid & 63;
  const int w    = tid >> 6;
  const int quad = lane >> 4;
  const int c    = lane & 15;
  const int wm   = w >> 1, wn = w & 1;

  const int m0 = blockIdx.y * 128;
  const int n0 = blockIdx.x * 128;
  const int sm  = tid >> 1;
  const int skb = (tid & 1) * 16;

  float4 xa[4];
  int4 wb[2];
  auto load_t = [&](int k0) {
    const float* xp = X + (size_t)(m0 + sm) * DIN + k0 + skb;
    xa[0] = *(const float4*)(xp + 0);
    xa[1] = *(const float4*)(xp + 4);
    xa[2] = *(const float4*)(xp + 8);
    xa[3] = *(const float4*)(xp + 12);
    const ushort_t* wp = Wz + (size_t)(n0 + sm) * 512 + k0 + skb;
    wb[0] = *(const int4*)wp;
    wb[1] = *(const int4*)(wp + 8);
  };
  auto store_t = [&](int buf) {
    __align__(16) ushort_t ta[16];
#pragma unroll
    for (int ii = 0; ii < 4; ++ii) {
      ta[ii * 4 + 0] = f2bu(xa[ii].x);
      ta[ii * 4 + 1] = f2bu(xa[ii].y);
      ta[ii * 4 + 2] = f2bu(xa[ii].z);
      ta[ii * 4 + 3] = f2bu(xa[ii].w);
    }
    *(int4*)(&As[buf * 5120 + sm * 40 + skb])     = ((int4*)ta)[0];
    *(int4*)(&As[buf * 5120 + sm * 40 + skb + 8]) = ((int4*)ta)[1];
    *(int4*)(&Bs[buf * 5120 + sm * 40 + skb])     = wb[0];
    *(int4*)(&Bs[buf * 5120 + sm * 40 + skb + 8]) = wb[1];
  };

  f32x4 acc[4][4];
#pragma unroll
  for (int m = 0; m < 4; ++m)
#pragma unroll
    for (int n = 0; n < 4; ++n) acc[m][n] = (f32x4)0.0f;

  load_t(0);
  store_t(0);
  __syncthreads();

  for (int t = 0; t < 16; ++t) {
    const int cur = t & 1;
    if (t < 15) load_t((t + 1) * 32);
    const ushort_t* as = As + cur * 5120;
    const ushort_t* bs = Bs + cur * 5120;
    short8 af[4], bfr[4];
#pragma unroll
    for (int m = 0; m < 4; ++m)
      af[m] = *(const short8*)(&as[(wm * 64 + m * 16 + c) * 40 + quad * 8]);
#pragma unroll
    for (int n = 0; n < 4; ++n)
      bfr[n] = *(const short8*)(&bs[(wn * 64 + n * 16 + c) * 40 + quad * 8]);
#pragma unroll
    for (int m = 0; m < 4; ++m)
#pragma unroll
      for (int n = 0; n < 4; ++n)
        acc[m][n] = __builtin_amdgcn_mfma_f32_16x16x32_bf16(af[m], bfr[n], acc[m][n], 0, 0, 0);
    if (t < 15) store_t(cur ^ 1);
    __syncthreads();
  }

#pragma unroll
  for (int m = 0; m < 4; ++m)
#pragma unroll
    for (int n = 0; n < 4; ++n)
#pragma unroll
      for (int r = 0; r < 4; ++r) {
        int row = m0 + wm * 64 + m * 16 + quad * 4 + r;
        int col = n0 + wn * 64 + n * 16 + c;
        Y[(size_t)row * HD + col] = f2bu(acc[m][n][r] * sc);
      }
}

// ---------------------------------------------------------------------------
// Kernel 1b: V transpose. Vf[(b*2048+t)*512 + cc] -> Vt[(b*512+cc)*2048 + t].
// ---------------------------------------------------------------------------
__global__ __launch_bounds__(256) void vtrans_kernel(
    const ushort_t* __restrict__ Vf, ushort_t* __restrict__ Vt) {
  const int b  = blockIdx.z;
  const int t0 = blockIdx.x * 64;
  const int c0 = blockIdx.y * 64;
  __shared__ ushort_t Ls[64 * 72];
  const int tid = threadIdx.x;
  {
    int r = tid >> 2, cb = (tid & 3) * 16;
    const ushort_t* src = Vf + (size_t)(b * NQ + t0 + r) * HD + c0 + cb;
    *(int4*)(&Ls[r * 72 + cb])     = *(const int4*)src;
    *(int4*)(&Ls[r * 72 + cb + 8]) = *(const int4*)(src + 8);
  }
  __syncthreads();
  {
    int rr = tid >> 2, tb = (tid & 3) * 16;
    __align__(16) ushort_t tmp[16];
#pragma unroll
    for (int j = 0; j < 16; ++j) tmp[j] = Ls[(tb + j) * 72 + rr];
    ushort_t* dst = Vt + (size_t)(b * HD + c0 + rr) * NKK + t0 + tb;
    *(int4*)dst       = ((int4*)tmp)[0];
    *(int4*)(dst + 8) = ((int4*)tmp)[1];
  }
}

// ---------------------------------------------------------------------------
// Kernel 2: MFMA flash attention, v3 — 32x32x16 MFMA, in-register softmax.
//  - 2 waves/block, 32 q-rows per wave (64/block); grid 32x8x4 = 1024 blocks.
//  - S^T = K @ Q^T via mfma_32x32x16: C col = q = lane&31,
//    row = key = (reg&3)+8*(reg>>2)+4*(lane>>5). Lane l and l^32 hold
//    complementary key halves of the same q column.
//  - P -> PV A-fragment entirely in registers: v_cvt_pk_bf16_f32 pairs +
//    v_permlane32_swap_b32 (T12). No P LDS buffer at all.
//  - K/V tiles in LDS, unpadded 64x64 rows (128B) with XOR swizzle
//    slot = c16 ^ (row&7) on write AND read (G4) -> 4-way max conflict.
//  - Double-buffered staging, one barrier per tile; no-max softmax.
// ---------------------------------------------------------------------------
__global__ __launch_bounds__(128) void attn_kernel(
    const ushort_t* __restrict__ Qf, const ushort_t* __restrict__ Kf,
    const ushort_t* __restrict__ Vt, ushort_t* __restrict__ CTX) {
  const int qb = blockIdx.x;
  const int h  = blockIdx.y;
  const int b  = blockIdx.z;

  __shared__ ushort_t Kt[2 * 64 * 64];  // [buf][key][d], swizzled 16B slots
  __shared__ ushort_t Vs[2 * 64 * 64];  // [buf][d][key], swizzled 16B slots

  const int tid  = threadIdx.x;   // 0..127
  const int lane = tid & 63;
  const int w    = tid >> 6;      // wave 0..1
  const int ql   = lane & 31;     // q (and B-col / A-row) index
  const int hi   = lane >> 5;     // lane half

  const int q0 = qb * 64 + w * 32;

  // Q as B operand: bq[ks] = Q[q0+ql][ks*16 + hi*8 .. +7]  (K=16 per step)
  short8 bq[4];
  {
    const ushort_t* qp = Qf + (size_t)(b * NQ + q0 + ql) * HD + h * HS + hi * 8;
#pragma unroll
    for (int ks = 0; ks < 4; ++ks) bq[ks] = *(const short8*)(qp + ks * 16);
  }

  f32x16 o[2];
  o[0] = (f32x16)0.0f;
  o[1] = (f32x16)0.0f;
  float lsum = 0.0f;

  int4 pk[4], pv[4];
  auto load_t = [&](int kt) {
#pragma unroll
    for (int i = 0; i < 4; ++i) {
      int g = i * 128 + tid, row = g >> 3, c = g & 7;
      pk[i] = *(const int4*)(Kf + (size_t)(b * NKK + kt * 64 + row) * HD + h * HS + c * 8);
      pv[i] = *(const int4*)(Vt + (size_t)((b * NH + h) * HS + row) * NKK + kt * 64 + c * 8);
    }
  };
  auto store_t = [&](int buf) {
#pragma unroll
    for (int i = 0; i < 4; ++i) {
      int g = i * 128 + tid, row = g >> 3, c = g & 7;
      int sl = row * 64 + ((c ^ (row & 7)) * 8);
      *(int4*)(&Kt[buf * 4096 + sl]) = pk[i];
      *(int4*)(&Vs[buf * 4096 + sl]) = pv[i];
    }
  };

  load_t(0);
  store_t(0);
  __syncthreads();

  for (int kt = 0; kt < NKK / 64; ++kt) {
    const int cur = kt & 1;
    if (kt < NKK / 64 - 1) load_t(kt + 1);  // prefetch next tile into regs
    const ushort_t* kb = &Kt[cur * 4096];
    const ushort_t* vb = &Vs[cur * 4096];

    // S^T = K @ Q^T : A = K [key][d], B = Q^T (regs). 2 key-groups of 32.
    f32x16 s[2];
    s[0] = (f32x16)0.0f;
    s[1] = (f32x16)0.0f;
    __builtin_amdgcn_s_setprio(1);
#pragma unroll
    for (int kg = 0; kg < 2; ++kg)
#pragma unroll
      for (int ks = 0; ks < 4; ++ks) {
        int row = kg * 32 + ql;
        short8 ak = *(const short8*)(&kb[row * 64 + (((ks * 2 + hi) ^ (row & 7)) * 8)]);
        s[kg] = __builtin_amdgcn_mfma_f32_32x32x16_bf16(ak, bq[ks], s[kg], 0, 0, 0);
      }
    __builtin_amdgcn_s_setprio(0);

    // Softmax (no-max) + in-register repack to PV A-fragments.
    // Lane holds p at key32 = (reg&3)+8*(reg>>2)+4*hi for its q=ql.
    // A-frag for k-step ks needs key = ks*16 + 8*hi + j  (j=0..7):
    //   reg = 4*(2*(ks&1)+hi) + (j&3), from lane-half hi_src = j>>2.
    // swap(wA,wC) -> words j01 (both halves) and j45; swap(wB,wD) -> j23,j67.
    short8 pa[4];
#pragma unroll
    for (int kg = 0; kg < 2; ++kg) {
      float p[16];
#pragma unroll
      for (int r = 0; r < 16; ++r) p[r] = __expf(s[kg][r]);
      // tree-sum into running denominator
      float a0 = p[0] + p[1], a1 = p[2] + p[3], a2 = p[4] + p[5], a3 = p[6] + p[7];
      float a4 = p[8] + p[9], a5 = p[10] + p[11], a6 = p[12] + p[13], a7 = p[14] + p[15];
      a0 += a1; a2 += a3; a4 += a5; a6 += a7;
      lsum += (a0 + a2) + (a4 + a6);
#pragma unroll
      for (int sp = 0; sp < 2; ++sp) {
        unsigned wA, wB, wC, wD;
        asm("v_cvt_pk_bf16_f32 %0, %1, %2" : "=v"(wA) : "v"(p[8 * sp + 0]), "v"(p[8 * sp + 1]));
        asm("v_cvt_pk_bf16_f32 %0, %1, %2" : "=v"(wB) : "v"(p[8 * sp + 2]), "v"(p[8 * sp + 3]));
        asm("v_cvt_pk_bf16_f32 %0, %1, %2" : "=v"(wC) : "v"(p[8 * sp + 4]), "v"(p[8 * sp + 5]));
        asm("v_cvt_pk_bf16_f32 %0, %1, %2" : "=v"(wD) : "v"(p[8 * sp + 6]), "v"(p[8 * sp + 7]));
        asm("v_permlane32_swap_b32 %0, %1" : "+v"(wA), "+v"(wC));
        asm("v_permlane32_swap_b32 %0, %1" : "+v"(wB), "+v"(wD));
        union { unsigned u[4]; short8 s8; } pu;
        pu.u[0] = wA;  // j0,j1
        pu.u[1] = wB;  // j2,j3
        pu.u[2] = wC;  // j4,j5
        pu.u[3] = wD;  // j6,j7
        pa[kg * 2 + sp] = pu.s8;
      }
    }

    // O += P @ V : A = P [q][key] (regs), B = V [key][d] read from Vs=[d][key].
    __builtin_amdgcn_s_setprio(1);
#pragma unroll
    for (int ng = 0; ng < 2; ++ng)
#pragma unroll
      for (int ks = 0; ks < 4; ++ks) {
        int row = ng * 32 + ql;
        short8 bv = *(const short8*)(&vb[row * 64 + (((ks * 2 + hi) ^ (row & 7)) * 8)]);
        o[ng] = __builtin_amdgcn_mfma_f32_32x32x16_bf16(pa[ks], bv, o[ng], 0, 0, 0);
      }
    __builtin_amdgcn_s_setprio(0);

    if (kt < NKK / 64 - 1) store_t(cur ^ 1);  // waits vmcnt, fills other buffer
    __syncthreads();
  }

  // Denominator: lane + lane^32 cover all 2048 keys of column q=ql.
  float tot = lsum + __shfl_xor(lsum, 32);
  float inv = 1.0f / tot;

  // O layout: row q = (reg&3)+8*(reg>>2)+4*hi, col d = ng*32 + ql.
#pragma unroll
  for (int r = 0; r < 16; ++r) {
    int qr = (r & 3) + 8 * (r >> 2) + 4 * hi;
    float iv = __shfl(inv, qr);
    size_t base = (size_t)(b * NQ + q0 + qr) * HD + h * HS + ql;
    CTX[base]      = f2bu(o[0][r] * iv);
    CTX[base + 32] = f2bu(o[1][r] * iv);
  }
}

// ---------------------------------------------------------------------------
// Kernel 3: out[8192,64] = CTX[8192,512] @ Wh[512,64], LDS-free MFMA.
// ---------------------------------------------------------------------------
__global__ __launch_bounds__(64) void outproj_kernel(
    const ushort_t* __restrict__ CTX, const ushort_t* __restrict__ Wht,
    float* __restrict__ out) {
  const int lane = threadIdx.x & 63;
  const int quad = lane >> 4, c = lane & 15;
  const int m0 = blockIdx.x * 16;

  f32x4 o[4];
#pragma unroll
  for (int n = 0; n < 4; ++n) o[n] = (f32x4)0.0f;

  const ushort_t* arow = CTX + (size_t)(m0 + c) * HD;
#pragma unroll 4
  for (int ks = 0; ks < 16; ++ks) {
    short8 a = *(const short8*)(arow + ks * 32 + quad * 8);
#pragma unroll
    for (int nd = 0; nd < 4; ++nd) {
      short8 bn = *(const short8*)(Wht + (size_t)(nd * 16 + c) * 512 + ks * 32 + quad * 8);
      o[nd] = __builtin_amdgcn_mfma_f32_16x16x32_bf16(a, bn, o[nd], 0, 0, 0);
    }
  }
#pragma unroll
  for (int nd = 0; nd < 4; ++nd)
#pragma unroll
    for (int r = 0; r < 4; ++r)
      out[(size_t)(m0 + quad * 4 + r) * HS + nd * 16 + c] = o[nd][r];
}

// ---------------------------------------------------------------------------
extern "C" void kernel_launch(void* const* d_in, const int* in_sizes, int n_in,
                              void* d_out, int out_size, void* d_ws,
                              size_t ws_size, hipStream_t stream) {
  const float* q  = (const float*)d_in[0];
  const float* k  = (const float*)d_in[1];
  const float* Wq = (const float*)d_in[2];
  const float* Wk = (const float*)d_in[3];
  const float* Wv = (const float*)d_in[4];
  const float* Wh = (const float*)d_in[5];
  float* out = (float*)d_out;

  // Workspace (bf16/ushort): Qf|Kf|Vt|CTX|Vf (each 8 MiB) + Wt (1.5 MiB) + Wht
  const size_t E = (size_t)BB * NQ * HD;
  ushort_t* ws  = (ushort_t*)d_ws;
  ushort_t* Qf  = ws;
  ushort_t* Kf  = Qf + E;
  ushort_t* Vt  = Kf + E;
  ushort_t* CTX = Vt + E;
  ushort_t* Vf  = CTX + E;
  ushort_t* Wt  = Vf + E;                      // 3 x 512 x 512
  ushort_t* Wht = Wt + (size_t)3 * 512 * 512;  // 64 x 512

  wtrans_kernel<<<dim3(8, 8, 4), 256, 0, stream>>>(Wq, Wk, Wv, Wh, Wt, Wht);
  proj_kernel<<<dim3(HD / 128, BB * NQ / 128, 3), 256, 0, stream>>>(
      q, k, Wt, Qf, Kf, Vf);
  vtrans_kernel<<<dim3(NKK / 64, HD / 64, BB), 256, 0, stream>>>(Vf, Vt);
  attn_kernel<<<dim3(NQ / 64, NH, BB), 128, 0, stream>>>(Qf, Kf, Vt, CTX);
  outproj_kernel<<<dim3(BB * NQ / 16), 64, 0, stream>>>(CTX, Wht, out);
}

// Round 2
// 203.666 us; speedup vs baseline: 1.4248x; 1.4248x over previous
//
#include <hip/hip_runtime.h>
#include <hip/hip_bf16.h>

// Problem constants (set_attention): B=4, Nq=Nk=2048, D_IN=512, H=8, HS=64
#define BB   4
#define NQ   2048
#define NKK  2048
#define DIN  512
#define NH   8
#define HS   64
#define HD   512  // NH*HS

typedef __hip_bfloat16 bf16;
typedef unsigned short ushort_t;
typedef __attribute__((ext_vector_type(8))) short short8;   // 8 bf16 (4 VGPRs)
typedef __attribute__((ext_vector_type(4))) float f32x4;    // MFMA 16x16 C/D
typedef __attribute__((ext_vector_type(16))) float f32x16;  // MFMA 32x32 C/D
typedef __attribute__((ext_vector_type(4))) unsigned u32x4;

__device__ __forceinline__ unsigned short f2bu(float x) {
  bf16 h = __float2bfloat16(x);
  return *(unsigned short*)&h;
}

// ---------------------------------------------------------------------------
// Kernel 0: weight transpose + bf16 convert.
// z<3:  W[512k][512n] f32 -> Wt_z[n][k] bf16   (64x64 tiles via LDS)
// z==3: Wh[512k][64n] f32 -> Wht[n][k] bf16
// ---------------------------------------------------------------------------
__global__ __launch_bounds__(256) void wtrans_kernel(
    const float* __restrict__ Wq, const float* __restrict__ Wk,
    const float* __restrict__ Wv, const float* __restrict__ Wh,
    ushort_t* __restrict__ Wt, ushort_t* __restrict__ Wht) {
  const int z = blockIdx.z;
  const float* src;
  ushort_t* dst;
  int S;  // source row length (n-dim)
  if (z < 3) {
    src = (z == 0) ? Wq : (z == 1) ? Wk : Wv;
    dst = Wt + (size_t)z * 512 * 512;
    S = 512;
  } else {
    if (blockIdx.y != 0) return;
    src = Wh;
    dst = Wht;
    S = 64;
  }
  const int k0 = blockIdx.x * 64;
  const int n0 = (z < 3) ? blockIdx.y * 64 : 0;

  __shared__ ushort_t Ls[64 * 72];
  const int tid = threadIdx.x;
  {
    int r = tid >> 2, cb = (tid & 3) * 16;
    const float* sp = src + (size_t)(k0 + r) * S + n0 + cb;
#pragma unroll
    for (int ii = 0; ii < 4; ++ii) {
      float4 f = *(const float4*)(sp + ii * 4);
      __align__(8) ushort_t t4[4] = {f2bu(f.x), f2bu(f.y), f2bu(f.z), f2bu(f.w)};
      *(uint2*)(&Ls[r * 72 + cb + ii * 4]) = *(uint2*)t4;
    }
  }
  __syncthreads();
  {
    int rr = tid >> 2, tb = (tid & 3) * 16;
    __align__(16) ushort_t tmp[16];
#pragma unroll
    for (int j = 0; j < 16; ++j) tmp[j] = Ls[(tb + j) * 72 + rr];
    ushort_t* dp = dst + (size_t)(n0 + rr) * 512 + k0 + tb;
    *(int4*)dp       = ((int4*)tmp)[0];
    *(int4*)(dp + 8) = ((int4*)tmp)[1];
  }
}

// ---------------------------------------------------------------------------
// Kernel 1: QKV projections, bf16 MFMA, double-buffered. Y = X @ W.
// ---------------------------------------------------------------------------
__global__ __launch_bounds__(256) void proj_kernel(
    const float* __restrict__ q, const float* __restrict__ k,
    const ushort_t* __restrict__ Wt, ushort_t* __restrict__ Qf,
    ushort_t* __restrict__ Kf, ushort_t* __restrict__ Vf) {
  const int z = blockIdx.z;
  const float* X = (z == 0) ? q : k;
  const ushort_t* Wz = Wt + (size_t)z * 512 * 512;
  ushort_t* Y = (z == 0) ? Qf : (z == 1) ? Kf : Vf;
  const float sc = (z == 0) ? 0.125f : 1.0f;  // fold 1/sqrt(64) into Q

  __shared__ ushort_t As[2 * 128 * 40];  // [buf][m][k]
  __shared__ ushort_t Bs[2 * 128 * 40];  // [buf][n][k]

  const int tid  = threadIdx.x;
  const int lane = tid & 63;
  const int w    = tid >> 6;
  const int quad = lane >> 4;
  const int c    = lane & 15;
  const int wm   = w >> 1, wn = w & 1;

  const int m0 = blockIdx.y * 128;
  const int n0 = blockIdx.x * 128;
  const int sm  = tid >> 1;
  const int skb = (tid & 1) * 16;

  float4 xa[4];
  int4 wb[2];
  auto load_t = [&](int k0) {
    const float* xp = X + (size_t)(m0 + sm) * DIN + k0 + skb;
    xa[0] = *(const float4*)(xp + 0);
    xa[1] = *(const float4*)(xp + 4);
    xa[2] = *(const float4*)(xp + 8);
    xa[3] = *(const float4*)(xp + 12);
    const ushort_t* wp = Wz + (size_t)(n0 + sm) * 512 + k0 + skb;
    wb[0] = *(const int4*)wp;
    wb[1] = *(const int4*)(wp + 8);
  };
  auto store_t = [&](int buf) {
    __align__(16) ushort_t ta[16];
#pragma unroll
    for (int ii = 0; ii < 4; ++ii) {
      ta[ii * 4 + 0] = f2bu(xa[ii].x);
      ta[ii * 4 + 1] = f2bu(xa[ii].y);
      ta[ii * 4 + 2] = f2bu(xa[ii].z);
      ta[ii * 4 + 3] = f2bu(xa[ii].w);
    }
    *(int4*)(&As[buf * 5120 + sm * 40 + skb])     = ((int4*)ta)[0];
    *(int4*)(&As[buf * 5120 + sm * 40 + skb + 8]) = ((int4*)ta)[1];
    *(int4*)(&Bs[buf * 5120 + sm * 40 + skb])     = wb[0];
    *(int4*)(&Bs[buf * 5120 + sm * 40 + skb + 8]) = wb[1];
  };

  f32x4 acc[4][4];
#pragma unroll
  for (int m = 0; m < 4; ++m)
#pragma unroll
    for (int n = 0; n < 4; ++n) acc[m][n] = (f32x4)0.0f;

  load_t(0);
  store_t(0);
  __syncthreads();

  for (int t = 0; t < 16; ++t) {
    const int cur = t & 1;
    if (t < 15) load_t((t + 1) * 32);
    const ushort_t* as = As + cur * 5120;
    const ushort_t* bs = Bs + cur * 5120;
    short8 af[4], bfr[4];
#pragma unroll
    for (int m = 0; m < 4; ++m)
      af[m] = *(const short8*)(&as[(wm * 64 + m * 16 + c) * 40 + quad * 8]);
#pragma unroll
    for (int n = 0; n < 4; ++n)
      bfr[n] = *(const short8*)(&bs[(wn * 64 + n * 16 + c) * 40 + quad * 8]);
#pragma unroll
    for (int m = 0; m < 4; ++m)
#pragma unroll
      for (int n = 0; n < 4; ++n)
        acc[m][n] = __builtin_amdgcn_mfma_f32_16x16x32_bf16(af[m], bfr[n], acc[m][n], 0, 0, 0);
    if (t < 15) store_t(cur ^ 1);
    __syncthreads();
  }

#pragma unroll
  for (int m = 0; m < 4; ++m)
#pragma unroll
    for (int n = 0; n < 4; ++n)
#pragma unroll
      for (int r = 0; r < 4; ++r) {
        int row = m0 + wm * 64 + m * 16 + quad * 4 + r;
        int col = n0 + wn * 64 + n * 16 + c;
        Y[(size_t)row * HD + col] = f2bu(acc[m][n][r] * sc);
      }
}

// ---------------------------------------------------------------------------
// Kernel 1b: V transpose. Vf[(b*2048+t)*512 + cc] -> Vt[(b*512+cc)*2048 + t].
// ---------------------------------------------------------------------------
__global__ __launch_bounds__(256) void vtrans_kernel(
    const ushort_t* __restrict__ Vf, ushort_t* __restrict__ Vt) {
  const int b  = blockIdx.z;
  const int t0 = blockIdx.x * 64;
  const int c0 = blockIdx.y * 64;
  __shared__ ushort_t Ls[64 * 72];
  const int tid = threadIdx.x;
  {
    int r = tid >> 2, cb = (tid & 3) * 16;
    const ushort_t* src = Vf + (size_t)(b * NQ + t0 + r) * HD + c0 + cb;
    *(int4*)(&Ls[r * 72 + cb])     = *(const int4*)src;
    *(int4*)(&Ls[r * 72 + cb + 8]) = *(const int4*)(src + 8);
  }
  __syncthreads();
  {
    int rr = tid >> 2, tb = (tid & 3) * 16;
    __align__(16) ushort_t tmp[16];
#pragma unroll
    for (int j = 0; j < 16; ++j) tmp[j] = Ls[(tb + j) * 72 + rr];
    ushort_t* dst = Vt + (size_t)(b * HD + c0 + rr) * NKK + t0 + tb;
    *(int4*)dst       = ((int4*)tmp)[0];
    *(int4*)(dst + 8) = ((int4*)tmp)[1];
  }
}

// ---------------------------------------------------------------------------
// Kernel 2: MFMA flash attention, v4 — 32x32x16, in-register softmax,
// global_load_lds staging (no reg staging, no P LDS, no spills).
//  - 2 waves/block, 32 q-rows per wave; grid 32x8x4 = 1024 blocks.
//  - K/V LDS tiles 64x64, linear global_load_lds dest + PRE-SWIZZLED global
//    source column (csrc = slot ^ (row&7)); reads use the same XOR (rule 21).
//  - S^T = K @ Q^T via mfma_32x32x16; P -> PV A-frag via v_cvt_pk_bf16_f32 +
//    v_permlane32_swap_b32 (T12), repacked with __builtin_bit_cast (no union,
//    no scratch).
//  - kg processed sequentially (one f32x16 S live at a time): QK^T(kg) ->
//    softmax(kg) -> PV(ks=2kg, 2kg+1), halving register pressure.
// ---------------------------------------------------------------------------
__global__ __launch_bounds__(128) void attn_kernel(
    const ushort_t* __restrict__ Qf, const ushort_t* __restrict__ Kf,
    const ushort_t* __restrict__ Vt, ushort_t* __restrict__ CTX) {
  const int qb = blockIdx.x;
  const int h  = blockIdx.y;
  const int b  = blockIdx.z;

  __shared__ ushort_t Kt[2 * 64 * 64];  // [buf][key][d] 16B slots, swizzled
  __shared__ ushort_t Vs[2 * 64 * 64];  // [buf][d][key] 16B slots, swizzled

  const int tid  = threadIdx.x;   // 0..127
  const int lane = tid & 63;
  const int w    = tid >> 6;      // wave 0..1
  const int ql   = lane & 31;     // q (and A-row / B-col) index
  const int hi   = lane >> 5;     // lane half

  const int q0 = qb * 64 + w * 32;

  // Q as B operand: bq[ks] = Q[q0+ql][ks*16 + hi*8 .. +7]  (K=16 per step)
  short8 bq[4];
  {
    const ushort_t* qp = Qf + (size_t)(b * NQ + q0 + ql) * HD + h * HS + hi * 8;
#pragma unroll
    for (int ks = 0; ks < 4; ++ks) bq[ks] = *(const short8*)(qp + ks * 16);
  }

  // Staging: per-wave 4 chunks of 8 rows x 64 cols each for K and V.
  // Lane covers (row = chunk*8 + sub, slot); source col pre-swizzled so the
  // linear LDS write lands data such that read slot = c ^ (row&7) is correct.
  const int sub  = lane >> 3;      // row within 8-row chunk == row & 7
  const int slot = lane & 7;       // 16B slot within row
  const int csrc = slot ^ sub;     // pre-swizzled source column (16B units)
  const ushort_t* kp0 =
      Kf + (size_t)(b * NKK + w * 32 + sub) * HD + h * HS + csrc * 8;
  const ushort_t* vp0 =
      Vt + (size_t)((b * NH + h) * HS + w * 32 + sub) * NKK + csrc * 8;

  auto stage = [&](int buf, int kt) {
    const ushort_t* kp = kp0 + (size_t)kt * 64 * HD;
    const ushort_t* vp = vp0 + (size_t)kt * 64;
#pragma unroll
    for (int i = 0; i < 4; ++i) {
      __builtin_amdgcn_global_load_lds(
          (const __attribute__((address_space(1))) unsigned*)(kp + (size_t)i * 8 * HD),
          (__attribute__((address_space(3))) unsigned*)(&Kt[buf * 4096 + (w * 4 + i) * 512]),
          16, 0, 0);
      __builtin_amdgcn_global_load_lds(
          (const __attribute__((address_space(1))) unsigned*)(vp + (size_t)i * 8 * NKK),
          (__attribute__((address_space(3))) unsigned*)(&Vs[buf * 4096 + (w * 4 + i) * 512]),
          16, 0, 0);
    }
  };

  f32x16 o0 = (f32x16)0.0f, o1 = (f32x16)0.0f;
  float lsum = 0.0f;

  stage(0, 0);
  __syncthreads();  // drains vmcnt before barrier

  for (int kt = 0; kt < NKK / 64; ++kt) {
    const int cur = kt & 1;
    if (kt < NKK / 64 - 1) stage(cur ^ 1, kt + 1);  // fly during compute
    const ushort_t* kb = &Kt[cur * 4096];
    const ushort_t* vb = &Vs[cur * 4096];

#pragma unroll
    for (int kg = 0; kg < 2; ++kg) {
      // S^T = K @ Q^T : A = K [key][d] from LDS, B = Q^T (regs).
      f32x16 s = (f32x16)0.0f;
      const int krow = kg * 32 + ql;
      __builtin_amdgcn_s_setprio(1);
#pragma unroll
      for (int ks = 0; ks < 4; ++ks) {
        short8 ak = *(const short8*)(&kb[krow * 64 + (((ks * 2 + hi) ^ (krow & 7)) * 8)]);
        s = __builtin_amdgcn_mfma_f32_32x32x16_bf16(ak, bq[ks], s, 0, 0, 0);
      }
      __builtin_amdgcn_s_setprio(0);

      // Softmax (no-max) + in-register repack to PV A-fragments.
      // Lane holds p at key32 = (reg&3)+8*(reg>>2)+4*hi for its q=ql.
      // A-frag for k-step ks needs key = ks*16 + 8*hi + j (j=0..7):
      //   reg = 4*(2*(ks&1)+hi) + (j&3), from lane-half hi_src = j>>2.
      // swap(wA,wC) -> words j01/j45 (both halves); swap(wB,wD) -> j23/j67.
      float p[16];
#pragma unroll
      for (int r = 0; r < 16; ++r) p[r] = __expf(s[r]);
      {
        float a0 = p[0] + p[1], a1 = p[2] + p[3], a2 = p[4] + p[5], a3 = p[6] + p[7];
        float a4 = p[8] + p[9], a5 = p[10] + p[11], a6 = p[12] + p[13], a7 = p[14] + p[15];
        a0 += a1; a2 += a3; a4 += a5; a6 += a7;
        lsum += (a0 + a2) + (a4 + a6);
      }
#pragma unroll
      for (int sp = 0; sp < 2; ++sp) {
        unsigned wA, wB, wC, wD;
        asm("v_cvt_pk_bf16_f32 %0, %1, %2" : "=v"(wA) : "v"(p[8 * sp + 0]), "v"(p[8 * sp + 1]));
        asm("v_cvt_pk_bf16_f32 %0, %1, %2" : "=v"(wB) : "v"(p[8 * sp + 2]), "v"(p[8 * sp + 3]));
        asm("v_cvt_pk_bf16_f32 %0, %1, %2" : "=v"(wC) : "v"(p[8 * sp + 4]), "v"(p[8 * sp + 5]));
        asm("v_cvt_pk_bf16_f32 %0, %1, %2" : "=v"(wD) : "v"(p[8 * sp + 6]), "v"(p[8 * sp + 7]));
        asm("v_permlane32_swap_b32 %0, %1" : "+v"(wA), "+v"(wC));
        asm("v_permlane32_swap_b32 %0, %1" : "+v"(wB), "+v"(wD));
        u32x4 pw;
        pw.x = wA;  // j0,j1
        pw.y = wB;  // j2,j3
        pw.z = wC;  // j4,j5
        pw.w = wD;  // j6,j7
        short8 pa = __builtin_bit_cast(short8, pw);

        // O += P @ V for this k-step: B = V [key][d] read from Vs=[d][key].
        const int ks = kg * 2 + sp;
        __builtin_amdgcn_s_setprio(1);
        {
          const int vrow0 = ql;        // d = 0..31
          short8 bv0 = *(const short8*)(&vb[vrow0 * 64 + (((ks * 2 + hi) ^ (vrow0 & 7)) * 8)]);
          o0 = __builtin_amdgcn_mfma_f32_32x32x16_bf16(pa, bv0, o0, 0, 0, 0);
          const int vrow1 = 32 + ql;   // d = 32..63
          short8 bv1 = *(const short8*)(&vb[vrow1 * 64 + (((ks * 2 + hi) ^ (vrow1 & 7)) * 8)]);
          o1 = __builtin_amdgcn_mfma_f32_32x32x16_bf16(pa, bv1, o1, 0, 0, 0);
        }
        __builtin_amdgcn_s_setprio(0);
      }
    }

    __syncthreads();  // drains vmcnt (next-tile stage) + lgkm, flips buffer
  }

  // Denominator: lane + lane^32 cover all 2048 keys of column q=ql.
  float tot = lsum + __shfl_xor(lsum, 32);
  float inv = 1.0f / tot;

  // O layout: row q = (reg&3)+8*(reg>>2)+4*hi, col d = ng*32 + ql.
#pragma unroll
  for (int r = 0; r < 16; ++r) {
    int qr = (r & 3) + 8 * (r >> 2) + 4 * hi;
    float iv = __shfl(inv, qr);
    size_t base = (size_t)(b * NQ + q0 + qr) * HD + h * HS + ql;
    CTX[base]      = f2bu(o0[r] * iv);
    CTX[base + 32] = f2bu(o1[r] * iv);
  }
}

// ---------------------------------------------------------------------------
// Kernel 3: out[8192,64] = CTX[8192,512] @ Wh[512,64], LDS-free MFMA.
// ---------------------------------------------------------------------------
__global__ __launch_bounds__(64) void outproj_kernel(
    const ushort_t* __restrict__ CTX, const ushort_t* __restrict__ Wht,
    float* __restrict__ out) {
  const int lane = threadIdx.x & 63;
  const int quad = lane >> 4, c = lane & 15;
  const int m0 = blockIdx.x * 16;

  f32x4 o[4];
#pragma unroll
  for (int n = 0; n < 4; ++n) o[n] = (f32x4)0.0f;

  const ushort_t* arow = CTX + (size_t)(m0 + c) * HD;
#pragma unroll 4
  for (int ks = 0; ks < 16; ++ks) {
    short8 a = *(const short8*)(arow + ks * 32 + quad * 8);
#pragma unroll
    for (int nd = 0; nd < 4; ++nd) {
      short8 bn = *(const short8*)(Wht + (size_t)(nd * 16 + c) * 512 + ks * 32 + quad * 8);
      o[nd] = __builtin_amdgcn_mfma_f32_16x16x32_bf16(a, bn, o[nd], 0, 0, 0);
    }
  }
#pragma unroll
  for (int nd = 0; nd < 4; ++nd)
#pragma unroll
    for (int r = 0; r < 4; ++r)
      out[(size_t)(m0 + quad * 4 + r) * HS + nd * 16 + c] = o[nd][r];
}

// ---------------------------------------------------------------------------
extern "C" void kernel_launch(void* const* d_in, const int* in_sizes, int n_in,
                              void* d_out, int out_size, void* d_ws,
                              size_t ws_size, hipStream_t stream) {
  const float* q  = (const float*)d_in[0];
  const float* k  = (const float*)d_in[1];
  const float* Wq = (const float*)d_in[2];
  const float* Wk = (const float*)d_in[3];
  const float* Wv = (const float*)d_in[4];
  const float* Wh = (const float*)d_in[5];
  float* out = (float*)d_out;

  // Workspace (bf16/ushort): Qf|Kf|Vt|CTX|Vf (each 8 MiB) + Wt (1.5 MiB) + Wht
  const size_t E = (size_t)BB * NQ * HD;
  ushort_t* ws  = (ushort_t*)d_ws;
  ushort_t* Qf  = ws;
  ushort_t* Kf  = Qf + E;
  ushort_t* Vt  = Kf + E;
  ushort_t* CTX = Vt + E;
  ushort_t* Vf  = CTX + E;
  ushort_t* Wt  = Vf + E;                      // 3 x 512 x 512
  ushort_t* Wht = Wt + (size_t)3 * 512 * 512;  // 64 x 512

  wtrans_kernel<<<dim3(8, 8, 4), 256, 0, stream>>>(Wq, Wk, Wv, Wh, Wt, Wht);
  proj_kernel<<<dim3(HD / 128, BB * NQ / 128, 3), 256, 0, stream>>>(
      q, k, Wt, Qf, Kf, Vf);
  vtrans_kernel<<<dim3(NKK / 64, HD / 64, BB), 256, 0, stream>>>(Vf, Vt);
  attn_kernel<<<dim3(NQ / 64, NH, BB), 128, 0, stream>>>(Qf, Kf, Vt, CTX);
  outproj_kernel<<<dim3(BB * NQ / 16), 64, 0, stream>>>(CTX, Wht, out);
}

// Round 4
// 202.900 us; speedup vs baseline: 1.4301x; 1.0038x over previous
//
#include <hip/hip_runtime.h>
#include <hip/hip_bf16.h>

// Problem constants (set_attention): B=4, Nq=Nk=2048, D_IN=512, H=8, HS=64
#define BB   4
#define NQ   2048
#define NKK  2048
#define DIN  512
#define NH   8
#define HS   64
#define HD   512  // NH*HS

typedef __hip_bfloat16 bf16;
typedef unsigned short ushort_t;
typedef __attribute__((ext_vector_type(8))) short short8;   // 8 bf16 (4 VGPRs)
typedef __attribute__((ext_vector_type(4))) float f32x4;    // MFMA 16x16 C/D
typedef __attribute__((ext_vector_type(16))) float f32x16;  // MFMA 32x32 C/D
typedef __attribute__((ext_vector_type(4))) unsigned u32x4;

__device__ __forceinline__ unsigned short f2bu(float x) {
  bf16 h = __float2bfloat16(x);
  return *(unsigned short*)&h;
}

// ---------------------------------------------------------------------------
// Kernel 0: weight transpose + bf16 convert.
// z<3:  W[512k][512n] f32 -> Wt_z[n][k] bf16   (64x64 tiles via LDS)
// z==3: Wh[512k][64n] f32 -> Wht[n][k] bf16
// ---------------------------------------------------------------------------
__global__ __launch_bounds__(256) void wtrans_kernel(
    const float* __restrict__ Wq, const float* __restrict__ Wk,
    const float* __restrict__ Wv, const float* __restrict__ Wh,
    ushort_t* __restrict__ Wt, ushort_t* __restrict__ Wht) {
  const int z = blockIdx.z;
  const float* src;
  ushort_t* dst;
  int S;  // source row length (n-dim)
  if (z < 3) {
    src = (z == 0) ? Wq : (z == 1) ? Wk : Wv;
    dst = Wt + (size_t)z * 512 * 512;
    S = 512;
  } else {
    if (blockIdx.y != 0) return;
    src = Wh;
    dst = Wht;
    S = 64;
  }
  const int k0 = blockIdx.x * 64;
  const int n0 = (z < 3) ? blockIdx.y * 64 : 0;

  __shared__ ushort_t Ls[64 * 72];
  const int tid = threadIdx.x;
  {
    int r = tid >> 2, cb = (tid & 3) * 16;
    const float* sp = src + (size_t)(k0 + r) * S + n0 + cb;
#pragma unroll
    for (int ii = 0; ii < 4; ++ii) {
      float4 f = *(const float4*)(sp + ii * 4);
      __align__(8) ushort_t t4[4] = {f2bu(f.x), f2bu(f.y), f2bu(f.z), f2bu(f.w)};
      *(uint2*)(&Ls[r * 72 + cb + ii * 4]) = *(uint2*)t4;
    }
  }
  __syncthreads();
  {
    int rr = tid >> 2, tb = (tid & 3) * 16;
    __align__(16) ushort_t tmp[16];
#pragma unroll
    for (int j = 0; j < 16; ++j) tmp[j] = Ls[(tb + j) * 72 + rr];
    ushort_t* dp = dst + (size_t)(n0 + rr) * 512 + k0 + tb;
    *(int4*)dp       = ((int4*)tmp)[0];
    *(int4*)(dp + 8) = ((int4*)tmp)[1];
  }
}

// ---------------------------------------------------------------------------
// Kernel 1: QKV projections, bf16 MFMA, double-buffered. Y = X @ W.
// Q is scaled by (1/sqrt(64)) * log2(e) so attention can use exp2 directly.
// ---------------------------------------------------------------------------
__global__ __launch_bounds__(256) void proj_kernel(
    const float* __restrict__ q, const float* __restrict__ k,
    const ushort_t* __restrict__ Wt, ushort_t* __restrict__ Qf,
    ushort_t* __restrict__ Kf, ushort_t* __restrict__ Vf) {
  const int z = blockIdx.z;
  const float* X = (z == 0) ? q : k;
  const ushort_t* Wz = Wt + (size_t)z * 512 * 512;
  ushort_t* Y = (z == 0) ? Qf : (z == 1) ? Kf : Vf;
  // fold 1/sqrt(64) AND log2(e) into Q (attn uses exp2)
  const float sc = (z == 0) ? 0.18033688011112042f : 1.0f;

  __shared__ ushort_t As[2 * 128 * 40];  // [buf][m][k]
  __shared__ ushort_t Bs[2 * 128 * 40];  // [buf][n][k]

  const int tid  = threadIdx.x;
  const int lane = tid & 63;
  const int w    = tid >> 6;
  const int quad = lane >> 4;
  const int c    = lane & 15;
  const int wm   = w >> 1, wn = w & 1;

  const int m0 = blockIdx.y * 128;
  const int n0 = blockIdx.x * 128;
  const int sm  = tid >> 1;
  const int skb = (tid & 1) * 16;

  float4 xa[4];
  int4 wb[2];
  auto load_t = [&](int k0) {
    const float* xp = X + (size_t)(m0 + sm) * DIN + k0 + skb;
    xa[0] = *(const float4*)(xp + 0);
    xa[1] = *(const float4*)(xp + 4);
    xa[2] = *(const float4*)(xp + 8);
    xa[3] = *(const float4*)(xp + 12);
    const ushort_t* wp = Wz + (size_t)(n0 + sm) * 512 + k0 + skb;
    wb[0] = *(const int4*)wp;
    wb[1] = *(const int4*)(wp + 8);
  };
  auto store_t = [&](int buf) {
    __align__(16) ushort_t ta[16];
#pragma unroll
    for (int ii = 0; ii < 4; ++ii) {
      ta[ii * 4 + 0] = f2bu(xa[ii].x);
      ta[ii * 4 + 1] = f2bu(xa[ii].y);
      ta[ii * 4 + 2] = f2bu(xa[ii].z);
      ta[ii * 4 + 3] = f2bu(xa[ii].w);
    }
    *(int4*)(&As[buf * 5120 + sm * 40 + skb])     = ((int4*)ta)[0];
    *(int4*)(&As[buf * 5120 + sm * 40 + skb + 8]) = ((int4*)ta)[1];
    *(int4*)(&Bs[buf * 5120 + sm * 40 + skb])     = wb[0];
    *(int4*)(&Bs[buf * 5120 + sm * 40 + skb + 8]) = wb[1];
  };

  f32x4 acc[4][4];
#pragma unroll
  for (int m = 0; m < 4; ++m)
#pragma unroll
    for (int n = 0; n < 4; ++n) acc[m][n] = (f32x4)0.0f;

  load_t(0);
  store_t(0);
  __syncthreads();

  for (int t = 0; t < 16; ++t) {
    const int cur = t & 1;
    if (t < 15) load_t((t + 1) * 32);
    const ushort_t* as = As + cur * 5120;
    const ushort_t* bs = Bs + cur * 5120;
    short8 af[4], bfr[4];
#pragma unroll
    for (int m = 0; m < 4; ++m)
      af[m] = *(const short8*)(&as[(wm * 64 + m * 16 + c) * 40 + quad * 8]);
#pragma unroll
    for (int n = 0; n < 4; ++n)
      bfr[n] = *(const short8*)(&bs[(wn * 64 + n * 16 + c) * 40 + quad * 8]);
#pragma unroll
    for (int m = 0; m < 4; ++m)
#pragma unroll
      for (int n = 0; n < 4; ++n)
        acc[m][n] = __builtin_amdgcn_mfma_f32_16x16x32_bf16(af[m], bfr[n], acc[m][n], 0, 0, 0);
    if (t < 15) store_t(cur ^ 1);
    __syncthreads();
  }

#pragma unroll
  for (int m = 0; m < 4; ++m)
#pragma unroll
    for (int n = 0; n < 4; ++n)
#pragma unroll
      for (int r = 0; r < 4; ++r) {
        int row = m0 + wm * 64 + m * 16 + quad * 4 + r;
        int col = n0 + wn * 64 + n * 16 + c;
        Y[(size_t)row * HD + col] = f2bu(acc[m][n][r] * sc);
      }
}

// ---------------------------------------------------------------------------
// Kernel 1b: V transpose. Vf[(b*2048+t)*512 + cc] -> Vt[(b*512+cc)*2048 + t].
// ---------------------------------------------------------------------------
__global__ __launch_bounds__(256) void vtrans_kernel(
    const ushort_t* __restrict__ Vf, ushort_t* __restrict__ Vt) {
  const int b  = blockIdx.z;
  const int t0 = blockIdx.x * 64;
  const int c0 = blockIdx.y * 64;
  __shared__ ushort_t Ls[64 * 72];
  const int tid = threadIdx.x;
  {
    int r = tid >> 2, cb = (tid & 3) * 16;
    const ushort_t* src = Vf + (size_t)(b * NQ + t0 + r) * HD + c0 + cb;
    *(int4*)(&Ls[r * 72 + cb])     = *(const int4*)src;
    *(int4*)(&Ls[r * 72 + cb + 8]) = *(const int4*)(src + 8);
  }
  __syncthreads();
  {
    int rr = tid >> 2, tb = (tid & 3) * 16;
    __align__(16) ushort_t tmp[16];
#pragma unroll
    for (int j = 0; j < 16; ++j) tmp[j] = Ls[(tb + j) * 72 + rr];
    ushort_t* dst = Vt + (size_t)(b * HD + c0 + rr) * NKK + t0 + tb;
    *(int4*)dst       = ((int4*)tmp)[0];
    *(int4*)(dst + 8) = ((int4*)tmp)[1];
  }
}

// ---------------------------------------------------------------------------
// Kernel 2: MFMA flash attention, v5 — 64 q-rows per wave.
//  - 2 waves/block, 64 q/wave (2 q-subtiles of 32); grid 16x8x4 = 512 blocks.
//  - Each K fragment (ak) and V fragment (bv) feeds TWO MFMAs (one per
//    q-subtile): ds_read:MFMA ratio halves to 1:2 vs v4.
//  - K/V via global_load_lds, linear dest + pre-swizzled source column;
//    reads use slot ^ (row&7) (rule 21, unchanged from v4).
//  - Softmax uses exp2 (log2(e) folded into Q scale in proj): p = 2^s,
//    via __builtin_amdgcn_exp2f (v_exp_f32: D = 2^S0).
//  - P -> PV A-frag via v_cvt_pk_bf16_f32 + v_permlane32_swap_b32 (T12).
// ---------------------------------------------------------------------------
__global__ __launch_bounds__(128) void attn_kernel(
    const ushort_t* __restrict__ Qf, const ushort_t* __restrict__ Kf,
    const ushort_t* __restrict__ Vt, ushort_t* __restrict__ CTX) {
  const int qb = blockIdx.x;
  const int h  = blockIdx.y;
  const int b  = blockIdx.z;

  __shared__ ushort_t Kt[2 * 64 * 64];  // [buf][key][d] 16B slots, swizzled
  __shared__ ushort_t Vs[2 * 64 * 64];  // [buf][d][key] 16B slots, swizzled

  const int tid  = threadIdx.x;   // 0..127
  const int lane = tid & 63;
  const int w    = tid >> 6;      // wave 0..1
  const int ql   = lane & 31;     // q (and A-row / B-col) index
  const int hi   = lane >> 5;     // lane half

  const int q0 = qb * 128 + w * 64;  // wave owns q0 .. q0+63

  // Q as B operand: bq[qs][ks] = Q[q0+qs*32+ql][ks*16 + hi*8 .. +7]
  short8 bq[2][4];
#pragma unroll
  for (int qs = 0; qs < 2; ++qs) {
    const ushort_t* qp =
        Qf + (size_t)(b * NQ + q0 + qs * 32 + ql) * HD + h * HS + hi * 8;
#pragma unroll
    for (int ks = 0; ks < 4; ++ks) bq[qs][ks] = *(const short8*)(qp + ks * 16);
  }

  // Staging: per-wave 4 chunks of 8 rows x 64 cols each for K and V.
  const int sub  = lane >> 3;      // row within 8-row chunk == row & 7
  const int slot = lane & 7;       // 16B slot within row
  const int csrc = slot ^ sub;     // pre-swizzled source column (16B units)
  const ushort_t* kp0 =
      Kf + (size_t)(b * NKK + w * 32 + sub) * HD + h * HS + csrc * 8;
  const ushort_t* vp0 =
      Vt + (size_t)((b * NH + h) * HS + w * 32 + sub) * NKK + csrc * 8;

  auto stage = [&](int buf, int kt) {
    const ushort_t* kp = kp0 + (size_t)kt * 64 * HD;
    const ushort_t* vp = vp0 + (size_t)kt * 64;
#pragma unroll
    for (int i = 0; i < 4; ++i) {
      __builtin_amdgcn_global_load_lds(
          (const __attribute__((address_space(1))) unsigned*)(kp + (size_t)i * 8 * HD),
          (__attribute__((address_space(3))) unsigned*)(&Kt[buf * 4096 + (w * 4 + i) * 512]),
          16, 0, 0);
      __builtin_amdgcn_global_load_lds(
          (const __attribute__((address_space(1))) unsigned*)(vp + (size_t)i * 8 * NKK),
          (__attribute__((address_space(3))) unsigned*)(&Vs[buf * 4096 + (w * 4 + i) * 512]),
          16, 0, 0);
    }
  };

  f32x16 o[2][2];  // [qs][ng]
#pragma unroll
  for (int qs = 0; qs < 2; ++qs)
#pragma unroll
    for (int ng = 0; ng < 2; ++ng) o[qs][ng] = (f32x16)0.0f;
  float lsum[2] = {0.0f, 0.0f};

  stage(0, 0);
  __syncthreads();

  for (int kt = 0; kt < NKK / 64; ++kt) {
    const int cur = kt & 1;
    if (kt < NKK / 64 - 1) stage(cur ^ 1, kt + 1);  // fly during compute
    const ushort_t* kb = &Kt[cur * 4096];
    const ushort_t* vb = &Vs[cur * 4096];

#pragma unroll
    for (int kg = 0; kg < 2; ++kg) {
      // S^T = K @ Q^T for both q-subtiles, sharing each K fragment.
      f32x16 s[2];
      s[0] = (f32x16)0.0f;
      s[1] = (f32x16)0.0f;
      const int krow = kg * 32 + ql;
      __builtin_amdgcn_s_setprio(1);
#pragma unroll
      for (int ks = 0; ks < 4; ++ks) {
        short8 ak = *(const short8*)(&kb[krow * 64 + (((ks * 2 + hi) ^ (krow & 7)) * 8)]);
        s[0] = __builtin_amdgcn_mfma_f32_32x32x16_bf16(ak, bq[0][ks], s[0], 0, 0, 0);
        s[1] = __builtin_amdgcn_mfma_f32_32x32x16_bf16(ak, bq[1][ks], s[1], 0, 0, 0);
      }
      __builtin_amdgcn_s_setprio(0);

      // Softmax (no-max, exp2) + in-register repack to PV A-fragments.
      short8 pa[2][2];  // [qs][sp]
#pragma unroll
      for (int qs = 0; qs < 2; ++qs) {
        float p[16];
#pragma unroll
        for (int r = 0; r < 16; ++r) p[r] = __builtin_amdgcn_exp2f(s[qs][r]);
        {
          float a0 = p[0] + p[1], a1 = p[2] + p[3], a2 = p[4] + p[5], a3 = p[6] + p[7];
          float a4 = p[8] + p[9], a5 = p[10] + p[11], a6 = p[12] + p[13], a7 = p[14] + p[15];
          a0 += a1; a2 += a3; a4 += a5; a6 += a7;
          lsum[qs] += (a0 + a2) + (a4 + a6);
        }
#pragma unroll
        for (int sp = 0; sp < 2; ++sp) {
          unsigned wA, wB, wC, wD;
          asm("v_cvt_pk_bf16_f32 %0, %1, %2" : "=v"(wA) : "v"(p[8 * sp + 0]), "v"(p[8 * sp + 1]));
          asm("v_cvt_pk_bf16_f32 %0, %1, %2" : "=v"(wB) : "v"(p[8 * sp + 2]), "v"(p[8 * sp + 3]));
          asm("v_cvt_pk_bf16_f32 %0, %1, %2" : "=v"(wC) : "v"(p[8 * sp + 4]), "v"(p[8 * sp + 5]));
          asm("v_cvt_pk_bf16_f32 %0, %1, %2" : "=v"(wD) : "v"(p[8 * sp + 6]), "v"(p[8 * sp + 7]));
          asm("v_permlane32_swap_b32 %0, %1" : "+v"(wA), "+v"(wC));
          asm("v_permlane32_swap_b32 %0, %1" : "+v"(wB), "+v"(wD));
          u32x4 pw;
          pw.x = wA;  // j0,j1
          pw.y = wB;  // j2,j3
          pw.z = wC;  // j4,j5
          pw.w = wD;  // j6,j7
          pa[qs][sp] = __builtin_bit_cast(short8, pw);
        }
      }

      // O += P @ V : each V fragment feeds both q-subtiles.
      __builtin_amdgcn_s_setprio(1);
#pragma unroll
      for (int sp = 0; sp < 2; ++sp) {
        const int ks = kg * 2 + sp;
#pragma unroll
        for (int ng = 0; ng < 2; ++ng) {
          const int vrow = ng * 32 + ql;
          short8 bv = *(const short8*)(&vb[vrow * 64 + (((ks * 2 + hi) ^ (vrow & 7)) * 8)]);
          o[0][ng] = __builtin_amdgcn_mfma_f32_32x32x16_bf16(pa[0][sp], bv, o[0][ng], 0, 0, 0);
          o[1][ng] = __builtin_amdgcn_mfma_f32_32x32x16_bf16(pa[1][sp], bv, o[1][ng], 0, 0, 0);
        }
      }
      __builtin_amdgcn_s_setprio(0);
    }

    __syncthreads();  // drains vmcnt (next-tile stage) + lgkm, flips buffer
  }

  // Denominator: lane + lane^32 cover all 2048 keys of column q.
  float inv[2];
#pragma unroll
  for (int qs = 0; qs < 2; ++qs) {
    float tot = lsum[qs] + __shfl_xor(lsum[qs], 32);
    inv[qs] = 1.0f / tot;
  }

  // O layout: row q = (reg&3)+8*(reg>>2)+4*hi, col d = ng*32 + ql.
#pragma unroll
  for (int qs = 0; qs < 2; ++qs)
#pragma unroll
    for (int r = 0; r < 16; ++r) {
      int qr = (r & 3) + 8 * (r >> 2) + 4 * hi;
      float iv = __shfl(inv[qs], qr);
      size_t base = (size_t)(b * NQ + q0 + qs * 32 + qr) * HD + h * HS + ql;
      CTX[base]      = f2bu(o[qs][0][r] * iv);
      CTX[base + 32] = f2bu(o[qs][1][r] * iv);
    }
}

// ---------------------------------------------------------------------------
// Kernel 3: out[8192,64] = CTX[8192,512] @ Wh[512,64], LDS-free MFMA.
// ---------------------------------------------------------------------------
__global__ __launch_bounds__(64) void outproj_kernel(
    const ushort_t* __restrict__ CTX, const ushort_t* __restrict__ Wht,
    float* __restrict__ out) {
  const int lane = threadIdx.x & 63;
  const int quad = lane >> 4, c = lane & 15;
  const int m0 = blockIdx.x * 16;

  f32x4 o[4];
#pragma unroll
  for (int n = 0; n < 4; ++n) o[n] = (f32x4)0.0f;

  const ushort_t* arow = CTX + (size_t)(m0 + c) * HD;
#pragma unroll 4
  for (int ks = 0; ks < 16; ++ks) {
    short8 a = *(const short8*)(arow + ks * 32 + quad * 8);
#pragma unroll
    for (int nd = 0; nd < 4; ++nd) {
      short8 bn = *(const short8*)(Wht + (size_t)(nd * 16 + c) * 512 + ks * 32 + quad * 8);
      o[nd] = __builtin_amdgcn_mfma_f32_16x16x32_bf16(a, bn, o[nd], 0, 0, 0);
    }
  }
#pragma unroll
  for (int nd = 0; nd < 4; ++nd)
#pragma unroll
    for (int r = 0; r < 4; ++r)
      out[(size_t)(m0 + quad * 4 + r) * HS + nd * 16 + c] = o[nd][r];
}

// ---------------------------------------------------------------------------
extern "C" void kernel_launch(void* const* d_in, const int* in_sizes, int n_in,
                              void* d_out, int out_size, void* d_ws,
                              size_t ws_size, hipStream_t stream) {
  const float* q  = (const float*)d_in[0];
  const float* k  = (const float*)d_in[1];
  const float* Wq = (const float*)d_in[2];
  const float* Wk = (const float*)d_in[3];
  const float* Wv = (const float*)d_in[4];
  const float* Wh = (const float*)d_in[5];
  float* out = (float*)d_out;

  // Workspace (bf16/ushort): Qf|Kf|Vt|CTX|Vf (each 8 MiB) + Wt (1.5 MiB) + Wht
  const size_t E = (size_t)BB * NQ * HD;
  ushort_t* ws  = (ushort_t*)d_ws;
  ushort_t* Qf  = ws;
  ushort_t* Kf  = Qf + E;
  ushort_t* Vt  = Kf + E;
  ushort_t* CTX = Vt + E;
  ushort_t* Vf  = CTX + E;
  ushort_t* Wt  = Vf + E;                      // 3 x 512 x 512
  ushort_t* Wht = Wt + (size_t)3 * 512 * 512;  // 64 x 512

  wtrans_kernel<<<dim3(8, 8, 4), 256, 0, stream>>>(Wq, Wk, Wv, Wh, Wt, Wht);
  proj_kernel<<<dim3(HD / 128, BB * NQ / 128, 3), 256, 0, stream>>>(
      q, k, Wt, Qf, Kf, Vf);
  vtrans_kernel<<<dim3(NKK / 64, HD / 64, BB), 256, 0, stream>>>(Vf, Vt);
  attn_kernel<<<dim3(NQ / 128, NH, BB), 128, 0, stream>>>(Qf, Kf, Vt, CTX);
  outproj_kernel<<<dim3(BB * NQ / 16), 64, 0, stream>>>(CTX, Wht, out);
}